// Round 1
// baseline (3865.999 us; speedup 1.0000x reference)
//
#include <hip/hip_runtime.h>
#include <cstdint>
#include <cstddef>

#define BB 256
#define TT 2048
#define VV 128
#define HH 64

__device__ __forceinline__ float frcp(float x){ return __builtin_amdgcn_rcpf(x); }
__device__ __forceinline__ float sigm(float x){ return frcp(1.f + __expf(-x)); }
__device__ __forceinline__ float tanh_f(float x){ return 1.f - 2.f*frcp(1.f + __expf(2.f*x)); }

// raw barrier: lgkmcnt drain for LDS visibility, but NO vmcnt drain
// (keeps the x-prefetch pipeline async across barriers)
__device__ __forceinline__ void bar_lds(){
  asm volatile("s_waitcnt lgkmcnt(0)" ::: "memory");
  __builtin_amdgcn_s_barrier();
}

__device__ __forceinline__ void gload16(const float* g, float* l){
  __builtin_amdgcn_global_load_lds(
      (const __attribute__((address_space(1))) void*)g,
      (__attribute__((address_space(3))) void*)l, 16, 0, 0);
}

__global__ __launch_bounds__(256, 1) void lstm_k(
  const float* __restrict__ x,
  const float* __restrict__ W_f,  const float* __restrict__ b_f,
  const float* __restrict__ W_if, const float* __restrict__ b_if,
  const float* __restrict__ W_ic, const float* __restrict__ b_ic,
  const float* __restrict__ W_o,  const float* __restrict__ b_o,
  const float* __restrict__ W_out,const float* __restrict__ b_out,
  float* __restrict__ out)
{
  __shared__ __align__(16) float s_x[4][VV];   // x ring buffer (prefetch 2 ahead)
  __shared__ __align__(16) float s_h[HH];
  __shared__ float s_g[3][HH];                 // f, af, add (activated)
  __shared__ float s_logits[VV];

  const int tid = threadIdx.x;
  const int wv  = tid >> 6;     // wave role: 0=f 1=if 2=ic 3=o
  const int l   = tid & 63;
  const int row = blockIdx.x;

  const float* Wg = (wv==0)? W_f : (wv==1)? W_if : (wv==2)? W_ic : W_o;
  const float* bg = (wv==0)? b_f : (wv==1)? b_if : (wv==2)? b_ic : b_o;

  // gate weight column pinned in VGPRs: w[k] = Wg[k][l], k = 0..191
  float w[192];
  #pragma unroll
  for (int k=0;k<192;++k) w[k] = Wg[k*HH + l];
  const float bias = bg[l];

  // W_out slice: 2 threads per logit column j, 32 k's each
  const int j  = 32*wv + (l>>1);
  const int kh = (l&1)*32;
  float wo[32];
  #pragma unroll
  for (int m=0;m<32;++m) wo[m] = W_out[(size_t)(kh+m)*VV + j];
  const float bj = ((l&1)==0) ? b_out[j] : 0.f;

  if (tid < HH) s_h[tid] = 0.f;
  float c = 0.f;  // live only on wave 3

  const float* xrow = x  + (size_t)row*TT*VV;
  float*       orow = out+ (size_t)row*TT*VV;

  // drain weight loads so the loop's counted vmcnt sees only prefetches
  asm volatile("s_waitcnt vmcnt(0)" ::: "memory");

  // prefetch x_0, x_1 (wave0 lanes 0..31, 16B/lane)
  if (tid < 32) {
    gload16(xrow +      tid*4, &s_x[0][0]);
    gload16(xrow + VV + tid*4, &s_x[1][0]);
  }

  #pragma unroll 1
  for (int t=0; t<TT; ++t) {
    // wave0 tracks its prefetch queue: keep 1 in flight, wait for x_t
    if (wv==0) {
      if (t < TT-1) asm volatile("s_waitcnt vmcnt(1)" ::: "memory");
      else          asm volatile("s_waitcnt vmcnt(0)" ::: "memory");
    }
    bar_lds();   // publishes x_t and logits(t-1)

    // softmax + store for step t-1, rotating among waves 1..3 (wave0 = prefetcher)
    if (t > 0 && wv == 1 + ((t-1)%3)) {
      float z0 = s_logits[l], z1 = s_logits[HH+l];
      float m = fmaxf(z0,z1);
      #pragma unroll
      for (int d=1; d<64; d<<=1) m = fmaxf(m, __shfl_xor(m, d));
      float e0 = __expf(z0-m), e1 = __expf(z1-m);
      float sden = e0+e1;
      #pragma unroll
      for (int d=1; d<64; d<<=1) sden += __shfl_xor(sden, d);
      float rs = frcp(sden);
      float* op = orow + (size_t)(t-1)*VV;
      op[l]    = e0*rs;
      op[HH+l] = e1*rs;
    }

    // gate matmul: pre = bias + sum_k s[k]*w[k], s = [x_t | h]
    const float4* sx4 = (const float4*)(&s_x[t&3][0]);
    const float4* sh4 = (const float4*)(&s_h[0]);
    float a0=0.f,a1=0.f,a2=0.f,a3=0.f;
    #pragma unroll
    for (int k4=0;k4<32;++k4){
      float4 v = sx4[k4];
      a0 = fmaf(v.x, w[4*k4+0], a0);
      a1 = fmaf(v.y, w[4*k4+1], a1);
      a2 = fmaf(v.z, w[4*k4+2], a2);
      a3 = fmaf(v.w, w[4*k4+3], a3);
    }
    #pragma unroll
    for (int k4=0;k4<16;++k4){
      float4 v = sh4[k4];
      a0 = fmaf(v.x, w[128+4*k4+0], a0);
      a1 = fmaf(v.y, w[128+4*k4+1], a1);
      a2 = fmaf(v.z, w[128+4*k4+2], a2);
      a3 = fmaf(v.w, w[128+4*k4+3], a3);
    }
    float acc = bias + ((a0+a1)+(a2+a3));

    // issue prefetch for x_{t+2} (slot (t+2)&3 is not in use)
    if (wv==0 && t+2 < TT && l < 32) {
      gload16(xrow + (size_t)(t+2)*VV + l*4, &s_x[(t+2)&3][0]);
    }

    float g = (wv==2) ? tanh_f(acc) : sigm(acc);
    if (wv < 3) s_g[wv][l] = g;
    bar_lds();   // B1: f, af, add visible

    if (wv==3) {
      float f_  = s_g[0][l];
      float af_ = s_g[1][l];
      float ad_ = s_g[2][l];
      c = c*f_ + ad_*af_;
      float hv = tanh_f(c) * g;   // g = o
      s_h[l] = hv;
    }
    bar_lds();   // B2: h visible

    // logits: all waves, 2 threads per column j
    const float4* hh4 = (const float4*)(&s_h[kh]);
    float p0=0.f, p1=0.f;
    #pragma unroll
    for (int m4=0;m4<8;++m4){
      float4 v = hh4[m4];
      p0 = fmaf(v.x, wo[4*m4+0], p0);
      p0 = fmaf(v.y, wo[4*m4+1], p0);
      p1 = fmaf(v.z, wo[4*m4+2], p1);
      p1 = fmaf(v.w, wo[4*m4+3], p1);
    }
    float p = p0+p1;
    p += __shfl_xor(p, 1);
    if ((l&1)==0) s_logits[j] = p + bj;
    // next loop-top barrier publishes s_logits
  }

  // final softmax for t = TT-1
  bar_lds();
  if (wv == 1 + ((TT-1)%3)) {
    float z0 = s_logits[l], z1 = s_logits[HH+l];
    float m = fmaxf(z0,z1);
    #pragma unroll
    for (int d=1; d<64; d<<=1) m = fmaxf(m, __shfl_xor(m, d));
    float e0 = __expf(z0-m), e1 = __expf(z1-m);
    float sden = e0+e1;
    #pragma unroll
    for (int d=1; d<64; d<<=1) sden += __shfl_xor(sden, d);
    float rs = frcp(sden);
    float* op = orow + (size_t)(TT-1)*VV;
    op[l]    = e0*rs;
    op[HH+l] = e1*rs;
  }
}

extern "C" void kernel_launch(void* const* d_in, const int* in_sizes, int n_in,
                              void* d_out, int out_size, void* d_ws, size_t ws_size,
                              hipStream_t stream) {
  const float* x     = (const float*)d_in[0];
  const float* W_f   = (const float*)d_in[1];
  const float* b_f   = (const float*)d_in[2];
  const float* W_if  = (const float*)d_in[3];
  const float* b_if  = (const float*)d_in[4];
  const float* W_ic  = (const float*)d_in[5];
  const float* b_ic  = (const float*)d_in[6];
  const float* W_o   = (const float*)d_in[7];
  const float* b_o   = (const float*)d_in[8];
  const float* W_out = (const float*)d_in[9];
  const float* b_out = (const float*)d_in[10];
  float* out = (float*)d_out;

  hipLaunchKernelGGL(lstm_k, dim3(BB), dim3(256), 0, stream,
                     x, W_f, b_f, W_if, b_if, W_ic, b_ic, W_o, b_o,
                     W_out, b_out, out);
}

// Round 2
// 2047.949 us; speedup vs baseline: 1.8877x; 1.8877x over previous
//
#include <hip/hip_runtime.h>
#include <cstdint>
#include <cstddef>

#define BB 256
#define TT 2048
#define VV 128
#define HH 64

__device__ __forceinline__ float frcp(float x){ return __builtin_amdgcn_rcpf(x); }
__device__ __forceinline__ float sigm(float x){ return frcp(1.f + __expf(-x)); }
__device__ __forceinline__ float tanh_f(float x){ return 1.f - 2.f*frcp(1.f + __expf(2.f*x)); }

// barrier with LDS visibility but NO vmcnt drain (keeps prefetch async);
// sched_barrier stops the compiler hoisting LDS reads above the s_barrier
__device__ __forceinline__ void bar_lds(){
  asm volatile("s_waitcnt lgkmcnt(0)" ::: "memory");
  __builtin_amdgcn_s_barrier();
  __builtin_amdgcn_sched_barrier(0);
}

__device__ __forceinline__ void gload16(const float* g, float* l){
  __builtin_amdgcn_global_load_lds(
      (const __attribute__((address_space(1))) void*)g,
      (__attribute__((address_space(3))) void*)l, 16, 0, 0);
}

__global__ __launch_bounds__(512, 2) void lstm_k(
  const float* __restrict__ x,
  const float* __restrict__ W_f,  const float* __restrict__ b_f,
  const float* __restrict__ W_if, const float* __restrict__ b_if,
  const float* __restrict__ W_ic, const float* __restrict__ b_ic,
  const float* __restrict__ W_o,  const float* __restrict__ b_o,
  const float* __restrict__ W_out,const float* __restrict__ b_out,
  float* __restrict__ out)
{
  __shared__ __align__(16) float s_x[4][VV];   // x ring buffer (prefetch 2 ahead)
  __shared__ __align__(16) float s_h[HH];
  __shared__ __align__(16) float s_g[3][HH];   // f, af, add (activated)

  const int tid  = threadIdx.x;
  const int wv   = tid >> 6;          // 8 waves
  const int l    = tid & 63;
  const int g    = wv >> 1;           // gate: 0=f 1=if 2=ic 3=o
  const int colh = wv & 1;            // column half
  const int col  = colh*32 + (l>>1);  // output column 0..63
  const int kpar = l & 1;             // k-half: 0 -> k 0..95, 1 -> k 96..191
  const int row  = blockIdx.x;

  const float* Wg = (g==0)? W_f : (g==1)? W_if : (g==2)? W_ic : W_o;
  const float* bg = (g==0)? b_f : (g==1)? b_if : (g==2)? b_ic : b_o;

  // per-thread gate weights: w[m] = Wg[kpar*96+m][col]
  float w[96];
  #pragma unroll
  for (int m=0;m<96;++m) w[m] = Wg[(size_t)(kpar*96+m)*HH + col];
  const float bias = bg[col];

  // W_out slice: 4 threads per logit column j, 16 k's each
  const int j  = tid >> 2;            // 0..127
  const int kh = (tid & 3) * 16;
  float wo[16];
  #pragma unroll
  for (int m=0;m<16;++m) wo[m] = W_out[(size_t)(kh+m)*VV + j];
  const float bj = b_out[j];

  if (tid < HH) s_h[tid] = 0.f;
  float c = 0.f;                      // live on waves 6,7 (duplicated per lane pair)

  const float* xrow = x  + (size_t)row*TT*VV;
  float*       orow = out+ (size_t)row*TT*VV;

  // prefetch x_0, x_1 (wave0 lanes 0..31, 16B each)
  if (wv==0 && l<32) {
    gload16(xrow +      l*4, &s_x[0][0]);
    gload16(xrow + VV + l*4, &s_x[1][0]);
  }
  if (wv==0) asm volatile("s_waitcnt vmcnt(1)" ::: "memory"); // x0 landed
  bar_lds();

  #pragma unroll 1
  for (int t=0; t<TT; ++t) {
    // ---- gate partial sums: even lanes k 0..95 (x), odd lanes k 96..191 (x|h)
    const float4* sx4 = (const float4*)(&s_x[t&3][0]);
    const float4* sh4 = (const float4*)(&s_h[0]);
    const float4* pA  = kpar ? (sx4 + 24) : sx4;        // 8 vec4
    const float4* pB  = kpar ? sh4        : (sx4 + 8);  // 16 vec4
    float a0=0.f,a1=0.f,a2=0.f,a3=0.f;
    #pragma unroll
    for (int m=0;m<8;++m){
      float4 v = pA[m];
      a0 = fmaf(v.x, w[4*m+0], a0);
      a1 = fmaf(v.y, w[4*m+1], a1);
      a2 = fmaf(v.z, w[4*m+2], a2);
      a3 = fmaf(v.w, w[4*m+3], a3);
    }
    #pragma unroll
    for (int m=0;m<16;++m){
      float4 v = pB[m];
      a0 = fmaf(v.x, w[32+4*m+0], a0);
      a1 = fmaf(v.y, w[32+4*m+1], a1);
      a2 = fmaf(v.z, w[32+4*m+2], a2);
      a3 = fmaf(v.w, w[32+4*m+3], a3);
    }
    float p = (a0+a1)+(a2+a3);
    p += __shfl_xor(p, 1);            // combine k-halves; both lanes get full sum
    float acc = bias + p;
    float gv  = (g==2) ? tanh_f(acc) : sigm(acc);
    if (g<3 && kpar==0) s_g[g][col] = gv;

    // issue prefetch for x_{t+2} (slot (t+2)&3 long out of use)
    if (wv==0 && t+2<TT && l<32)
      gload16(xrow + (size_t)(t+2)*VV + l*4, &s_x[(t+2)&3][0]);

    bar_lds();   // B1: f, af, add visible

    if (g==3) {  // waves 6,7: c/h update, 32 cols each, both lanes duplicate c
      float f_  = s_g[0][col];
      float af_ = s_g[1][col];
      float ad_ = s_g[2][col];
      c = c*f_ + ad_*af_;
      float hv = tanh_f(c) * gv;      // gv = o
      if (kpar==0) s_h[col] = hv;
    }
    // wave0 idle here: counted wait so x_{t+1} is in LDS before B2
    if (wv==0) {
      if (t==0)          asm volatile("s_waitcnt vmcnt(1)" ::: "memory");
      else if (t+2<TT)   asm volatile("s_waitcnt vmcnt(2)" ::: "memory"); // {store(t-1), gload(t+2)}
      else if (t+1<TT)   asm volatile("s_waitcnt vmcnt(1)" ::: "memory"); // {store(t-1)}
    }
    bar_lds();   // B2: h visible (doubles as loop-top barrier)

    // ---- logits: 4 threads per column j, 16 k's each; write RAW logits to out
    const float4* hh4 = (const float4*)(&s_h[kh]);
    float p0=0.f, p1=0.f;
    #pragma unroll
    for (int m=0;m<4;++m){
      float4 v = hh4[m];
      p0 = fmaf(v.x, wo[4*m+0], p0);
      p0 = fmaf(v.y, wo[4*m+1], p0);
      p1 = fmaf(v.z, wo[4*m+2], p1);
      p1 = fmaf(v.w, wo[4*m+3], p1);
    }
    float pl = p0+p1;
    pl += __shfl_xor(pl, 1);
    pl += __shfl_xor(pl, 2);          // sum over the 4-thread quad
    if ((l&3)==0) orow[(size_t)t*VV + j] = pl + bj;
  }
}

// epilogue: in-place softmax over [B*T, 128]; one wave per row
__global__ __launch_bounds__(256) void softmax_k(float* __restrict__ out)
{
  const int r = blockIdx.x*4 + (threadIdx.x>>6);
  const int l = threadIdx.x & 63;
  float2* p = (float2*)(out + (size_t)r*VV);
  float2 v = p[l];
  float m = fmaxf(v.x, v.y);
  #pragma unroll
  for (int d=1; d<64; d<<=1) m = fmaxf(m, __shfl_xor(m, d));
  float e0 = __expf(v.x - m), e1 = __expf(v.y - m);
  float s = e0 + e1;
  #pragma unroll
  for (int d=1; d<64; d<<=1) s += __shfl_xor(s, d);
  float rs = frcp(s);
  p[l] = make_float2(e0*rs, e1*rs);
}

extern "C" void kernel_launch(void* const* d_in, const int* in_sizes, int n_in,
                              void* d_out, int out_size, void* d_ws, size_t ws_size,
                              hipStream_t stream) {
  const float* x     = (const float*)d_in[0];
  const float* W_f   = (const float*)d_in[1];
  const float* b_f   = (const float*)d_in[2];
  const float* W_if  = (const float*)d_in[3];
  const float* b_if  = (const float*)d_in[4];
  const float* W_ic  = (const float*)d_in[5];
  const float* b_ic  = (const float*)d_in[6];
  const float* W_o   = (const float*)d_in[7];
  const float* b_o   = (const float*)d_in[8];
  const float* W_out = (const float*)d_in[9];
  const float* b_out = (const float*)d_in[10];
  float* out = (float*)d_out;

  hipLaunchKernelGGL(lstm_k, dim3(BB), dim3(512), 0, stream,
                     x, W_f, b_f, W_if, b_if, W_ic, b_ic, W_o, b_o,
                     W_out, b_out, out);
  hipLaunchKernelGGL(softmax_k, dim3(BB*TT/4), dim3(256), 0, stream, out);
}